// Round 7
// baseline (271.713 us; speedup 1.0000x reference)
//
#include <hip/hip_runtime.h>
#include <math.h>

#define BB 64
#define RR 6912
#define II 8
#define CC 10
#define OO 16
#define RPB2 96         // routes per block (fused kernel)
#define NCH2 72         // RR / RPB2
#define NG2 12          // 2-route MFMA groups per wave (24 routes/wave x 4 waves)
#define NBLK 720        // CC * NCH2
#define NREP 9          // accumulator replicas (chunk % NREP) -> 128 RMWs/line
#define MRG_PAD 20
#define WTILE_I4 (RPB2*16)                 // 1536 int4 = 24 KB W tile
#define MRGF (4*64*MRG_PAD + 4*64)         // 5376 floats merge scratch
#define ACCW (CC*NREP*BB*OO)               // 92160 f32 per iteration
#define ZW   (CC*NREP*BB)                  // 5760 f32
#define ZWORDS (3*ACCW + 2*ZW + 8)         // zeroed region incl. counter

typedef _Float16 h2 __attribute__((ext_vector_type(2)));
typedef _Float16 half8 __attribute__((ext_vector_type(8)));
typedef float f32x16 __attribute__((ext_vector_type(16)));
union HV { int4 v; h2 h[4]; half8 h8; };

// Returning atomic add: RMW executes AT the coherent point (MALL); keeping the
// return value live forces the sc0 (returning) encoding, so vmcnt drain ==
// global visibility. (R3 precedent: RMW handoff is correct; R6's
// write-through-store + plain-load was not.)
__device__ __forceinline__ void addf(float* p, float v) {
    float old = __hip_atomic_fetch_add(p, v, __ATOMIC_RELAXED, __HIP_MEMORY_SCOPE_AGENT);
    asm volatile("" :: "v"(old));
}

// Grid barrier: __syncthreads drains vmcnt (all this block's data RMWs acked at
// MALL), then one returning RMW arrival + bounded spin. No fences, no L2
// writeback anywhere. Bounded guard: rocprof replay with stale cnt falls
// through in <~2ms instead of hanging; real runs never time out (prep zeroes
// cnt each launch; all 720 blocks are co-resident by launch_bounds).
__device__ __forceinline__ void gbar(unsigned* cnt, unsigned target) {
    __syncthreads();
    if (threadIdx.x == 0) {
        unsigned v = 1u + __hip_atomic_fetch_add(cnt, 1u, __ATOMIC_RELAXED,
                                                 __HIP_MEMORY_SCOPE_AGENT);
        int guard = 0;
        while (v < target && ++guard < (1 << 13)) {
            __builtin_amdgcn_s_sleep(2);
            v = __hip_atomic_load(cnt, __ATOMIC_RELAXED, __HIP_MEMORY_SCOPE_AGENT);
        }
    }
    __syncthreads();
}

// ---------------- prep kernel ----------------
// blocks [0,432): transpose+cvt x[B][R][8] f32 -> xth[R][B][8] f16
// blocks [432,1512): W convert W[c][r][i][o] f32 -> wh[c][r][o][i] f16
// all blocks: zero one strided slice of the acc/z/cnt region (plain stores;
// the dispatch-boundary cache flush publishes them before fused starts).
__global__ __launch_bounds__(256) void prep_kernel(
    const float* __restrict__ x, int4* __restrict__ xth4,
    const float4* __restrict__ w4, int4* __restrict__ wh4,
    float* __restrict__ zbase)
{
    __shared__ __align__(16) float4 lds4[64 * 34];
    const int t = threadIdx.x;
    const int bid = blockIdx.x;

    for (unsigned idx = (unsigned)bid * 256u + (unsigned)t; idx < (unsigned)ZWORDS;
         idx += 1512u * 256u)
        zbase[idx] = 0.f;

    if (bid < 432) {
        const int rblk = bid >> 2;
        const int bblk = bid & 3;
        const int r0 = rblk * 64, b0 = bblk * 16;
        {
            const int rl = t & 63;
            const int bl0 = t >> 6;
#pragma unroll
            for (int kb = 0; kb < 4; ++kb) {
                const int bl = kb * 4 + bl0;
                const float4* src = (const float4*)(x + ((size_t)(b0 + bl) * RR + (r0 + rl)) * II);
                lds4[rl * 34 + bl * 2 + 0] = src[0];
                lds4[rl * 34 + bl * 2 + 1] = src[1];
            }
        }
        __syncthreads();
        {
            const int bl = t & 15;
            const int rw0 = t >> 4;
#pragma unroll
            for (int kr = 0; kr < 4; ++kr) {
                const int rw = kr * 16 + rw0;
                float4 a = lds4[rw * 34 + bl * 2 + 0];
                float4 bq = lds4[rw * 34 + bl * 2 + 1];
                HV u;
                u.h[0] = h2{(_Float16)a.x,  (_Float16)a.y};
                u.h[1] = h2{(_Float16)a.z,  (_Float16)a.w};
                u.h[2] = h2{(_Float16)bq.x, (_Float16)bq.y};
                u.h[3] = h2{(_Float16)bq.z, (_Float16)bq.w};
                xth4[(size_t)(r0 + rw) * BB + (b0 + bl)] = u.v;
            }
        }
    } else {
        _Float16* wl = (_Float16*)lds4;
        const int wblk = bid - 432;          // 0..1079
        const int rp = t >> 5;
        const int i  = (t >> 2) & 7;
        const int o0 = (t & 3) * 4;
#pragma unroll 1
        for (int sb = 0; sb < 8; ++sb) {
            const int blk8 = wblk * 8 + sb;  // == c*864 + (r/8)
            const float4 v = w4[(size_t)blk8 * 256 + t];
            _Float16* wb = wl + (sb & 1) * 1024;
            wb[(rp * 16 + o0 + 0) * 8 + i] = (_Float16)v.x;
            wb[(rp * 16 + o0 + 1) * 8 + i] = (_Float16)v.y;
            wb[(rp * 16 + o0 + 2) * 8 + i] = (_Float16)v.z;
            wb[(rp * 16 + o0 + 3) * 8 + i] = (_Float16)v.w;
            __syncthreads();
            if (t < 128) wh4[(size_t)blk8 * 128 + t] = ((const int4*)wb)[t];
        }
    }
}

// ---------------- routing iteration ----------------
// MFMA structure identical to verified R1-R5 (2 routes block-diagonal per
// 32x32x16 f16, depth-1 x prefetch). Epilogue: LDS merge (verified R4 code)
// then 4 returning atomicAdds/thread into the replica accumulator.
template <int MODE>
__device__ __forceinline__ void it_phase(
    const int4* __restrict__ xth4, const int4* wlds, float* mrg,
    const float* __restrict__ ov,
    float* __restrict__ acc, float* __restrict__ zacc,
    int c, int chunk, int t)
{
    const int wv = t >> 6;
    const int l = t & 63;
    const int b = l & 31;
    const int hi = l >> 5;
    const int aquad = (l >> 4) & 1;
    const bool aact = (aquad == hi);

    float accA[8], accB[8];
#pragma unroll
    for (int j = 0; j < 8; ++j) { accA[j] = 0.f; accB[j] = 0.f; }
    float ZA = 0.f, ZB = 0.f;

    float ovA[8], ovB[8];
    if (MODE != 0) {
        const float* pa = ov + ((size_t)c * BB + b) * OO + 4 * hi;
        const float* pb = ov + ((size_t)c * BB + 32 + b) * OO + 4 * hi;
        float4 a0 = *(const float4*)(pa);
        float4 a1 = *(const float4*)(pa + 8);
        float4 b0 = *(const float4*)(pb);
        float4 b1 = *(const float4*)(pb + 8);
        ovA[0]=a0.x; ovA[1]=a0.y; ovA[2]=a0.z; ovA[3]=a0.w;
        ovA[4]=a1.x; ovA[5]=a1.y; ovA[6]=a1.z; ovA[7]=a1.w;
        ovB[0]=b0.x; ovB[1]=b0.y; ovB[2]=b0.z; ovB[3]=b0.w;
        ovB[4]=b1.x; ovB[5]=b1.y; ovB[6]=b1.z; ovB[7]=b1.w;
    }

    const int rbase = chunk * RPB2 + wv * 24;

    f32x16 cA, cB, zf;
#pragma unroll
    for (int q = 0; q < 16; ++q) { cA[q] = 0.f; cB[q] = 0.f; zf[q] = 0.f; }

    HV xc0, xc1, xn0, xn1;
    xc0.v = xth4[(size_t)(rbase + hi) * BB + b];
    xc1.v = xth4[(size_t)(rbase + hi) * BB + 32 + b];
    xn0 = xc0; xn1 = xc1;

#pragma unroll 1
    for (int g = 0; g < NG2; ++g) {
        if (g + 1 < NG2) {
            const int rn = rbase + (g + 1) * 2 + hi;
            xn0.v = xth4[(size_t)rn * BB + b];
            xn1.v = xth4[(size_t)rn * BB + 32 + b];
        }
        const int rl0 = wv * 24 + g * 2;
        HV wq;
        wq.v = wlds[(rl0 + aquad) * 16 + (l & 15)];
        if (!aact) wq.v = make_int4(0, 0, 0, 0);

        if (MODE == 0) {
            cA = __builtin_amdgcn_mfma_f32_32x32x16_f16(wq.h8, xc0.h8, cA, 0, 0, 0);
            cB = __builtin_amdgcn_mfma_f32_32x32x16_f16(wq.h8, xc1.h8, cB, 0, 0, 0);
        } else {
            f32x16 p0 = __builtin_amdgcn_mfma_f32_32x32x16_f16(wq.h8, xc0.h8, zf, 0, 0, 0);
            f32x16 p1 = __builtin_amdgcn_mfma_f32_32x32x16_f16(wq.h8, xc1.h8, zf, 0, 0, 0);
            float dA0 = 0.f, dA1 = 0.f, dB0 = 0.f, dB1 = 0.f;
#pragma unroll
            for (int j = 0; j < 8; ++j) {
                dA0 = fmaf(p0[j],     ovA[j], dA0);
                dA1 = fmaf(p0[j + 8], ovA[j], dA1);
                dB0 = fmaf(p1[j],     ovB[j], dB0);
                dB1 = fmaf(p1[j + 8], ovB[j], dB1);
            }
            dA0 += __shfl_xor(dA0, 32);
            dA1 += __shfl_xor(dA1, 32);
            dB0 += __shfl_xor(dB0, 32);
            dB1 += __shfl_xor(dB1, 32);
            const float eA0 = __expf(dA0), eA1 = __expf(dA1);
            const float eB0 = __expf(dB0), eB1 = __expf(dB1);
            ZA += eA0 + eA1; ZB += eB0 + eB1;
#pragma unroll
            for (int j = 0; j < 8; ++j) {
                accA[j] = fmaf(eA0, p0[j], fmaf(eA1, p0[j + 8], accA[j]));
                accB[j] = fmaf(eB0, p1[j], fmaf(eB1, p1[j + 8], accB[j]));
            }
        }
        xc0 = xn0; xc1 = xn1;
    }

    if (MODE == 0) {
#pragma unroll
        for (int j = 0; j < 8; ++j) {
            accA[j] = cA[j] + cA[j + 8];
            accB[j] = cB[j] + cB[j + 8];
        }
    }

    // LDS merge (rows are per-wave exclusive; previous phase's reads were
    // sealed by the last gbar's __syncthreads)
    {
        float* m0 = mrg + (wv * 64 + b) * MRG_PAD + 4 * hi;
        *(float4*)(m0)     = make_float4(accA[0], accA[1], accA[2], accA[3]);
        *(float4*)(m0 + 8) = make_float4(accA[4], accA[5], accA[6], accA[7]);
        float* m1 = mrg + (wv * 64 + 32 + b) * MRG_PAD + 4 * hi;
        *(float4*)(m1)     = make_float4(accB[0], accB[1], accB[2], accB[3]);
        *(float4*)(m1 + 8) = make_float4(accB[4], accB[5], accB[6], accB[7]);
        if (MODE != 0 && hi == 0) {
            float* zr = mrg + 4 * 64 * MRG_PAD;
            zr[wv * 64 + b] = ZA;
            zr[wv * 64 + 32 + b] = ZB;
        }
    }
    __syncthreads();

    // block partial -> replica accumulator via returning atomicAdd
    {
        const int b2 = t >> 2, q = t & 3;
        float4 sum = make_float4(0.f, 0.f, 0.f, 0.f);
#pragma unroll
        for (int w2 = 0; w2 < 4; ++w2) {
            const float4 v = *(const float4*)(mrg + (w2 * 64 + b2) * MRG_PAD + q * 4);
            sum.x += v.x; sum.y += v.y; sum.z += v.z; sum.w += v.w;
        }
        const int rep = chunk % NREP;
        float* dst = acc + (((size_t)c * NREP + rep) * BB + b2) * OO + q * 4;
        addf(dst + 0, sum.x);
        addf(dst + 1, sum.y);
        addf(dst + 2, sum.z);
        addf(dst + 3, sum.w);
        if (MODE != 0 && q == 0) {
            const float* zr = mrg + 4 * 64 * MRG_PAD;
            float z = 0.f;
#pragma unroll
            for (int w2 = 0; w2 < 4; ++w2) z += zr[w2 * 64 + b2];
            addf(zacc + ((size_t)c * NREP + rep) * BB + b2, z);
        }
    }
}

// ---------------- combine: block (c2,b2)=bid sums NREP replicas + squash ----------------
template <int MODE>
__device__ __forceinline__ void combine_phase(
    const float* __restrict__ acc, const float* __restrict__ zacc,
    const float* __restrict__ addv, float* __restrict__ dst, bool coh,
    int bid, int t, float* cl)
{
    const int c2 = bid >> 6, b2 = bid & 63;
    const int o = t & 15, g = t >> 4;

    float s = (g < NREP) ? acc[(((size_t)c2 * NREP + g) * BB + b2) * OO + o] : 0.f;
    cl[t] = s;
    if (MODE != 0 && o == 0)
        cl[256 + g] = (g < NREP) ? zacc[((size_t)c2 * NREP + g) * BB + b2] : 0.f;
    __syncthreads();

    if (g == 0) {
#pragma unroll
        for (int k = 1; k < NREP; ++k) s += cl[k * 16 + o];
        if (MODE != 0) {
            float Zt = 0.f;
#pragma unroll
            for (int k = 0; k < NREP; ++k) Zt += cl[256 + k];
            s /= Zt;
        } else {
            s *= (1.0f / RR);
        }
        float sq = s * s;
#pragma unroll
        for (int w = 1; w < 16; w <<= 1) sq += __shfl_xor(sq, w);
        float val = s * sqrtf(sq) / (1.f + sq);
        if (MODE == 1) val += addv[(size_t)bid * OO + o];
        if (coh) {
            float old = __hip_atomic_exchange(dst + (size_t)bid * OO + o, val,
                         __ATOMIC_RELAXED, __HIP_MEMORY_SCOPE_AGENT);
            asm volatile("" :: "v"(old));
        } else {
            dst[(size_t)bid * OO + o] = val;   // final output: dispatch-end flush
        }
    }
    __syncthreads();
}

// ---------------- fused routing kernel ----------------
// 720 blocks, all co-resident (launch_bounds(256,3): VGPR<=168, LDS 46KB ->
// 3 blocks/CU, capacity 768). W tile staged once, persists across all 3
// iterations. All cross-block handoff via returning RMWs (visibility = ack).
__global__ __launch_bounds__(256, 3) void fused_kernel(
    const int4* __restrict__ xth4, const int4* __restrict__ wh4,
    float* acc0, float* acc1, float* acc2, float* z1, float* z2,
    float* v0, float* outsum, float* out, unsigned* cnt)
{
    __shared__ __align__(16) int4 wlds[WTILE_I4];   // 24576 B
    __shared__ __align__(16) float mrg[MRGF];       // 21504 B
    __shared__ float cl[272];                       //  1088 B

    const int bid = blockIdx.x;
    const int t = threadIdx.x;
    const int chunk = bid / 10;
    const int c = bid - chunk * 10;

    {
        const int4* src = wh4 + ((size_t)c * RR + (size_t)chunk * RPB2) * 16;
#pragma unroll
        for (int k = 0; k < 6; ++k) wlds[k * 256 + t] = src[k * 256 + t];
    }
    __syncthreads();

    it_phase<0>(xth4, wlds, mrg, nullptr, acc0, nullptr, c, chunk, t);
    gbar(cnt, NBLK * 1);
    if (bid < CC * BB) combine_phase<0>(acc0, nullptr, nullptr, v0, true, bid, t, cl);
    gbar(cnt, NBLK * 2);
    it_phase<1>(xth4, wlds, mrg, v0, acc1, z1, c, chunk, t);
    gbar(cnt, NBLK * 3);
    if (bid < CC * BB) combine_phase<1>(acc1, z1, v0, outsum, true, bid, t, cl);
    gbar(cnt, NBLK * 4);
    it_phase<2>(xth4, wlds, mrg, outsum, acc2, z2, c, chunk, t);
    gbar(cnt, NBLK * 5);
    if (bid < CC * BB) combine_phase<2>(acc2, z2, nullptr, out, false, bid, t, cl);
}

extern "C" void kernel_launch(void* const* d_in, const int* in_sizes, int n_in,
                              void* d_out, int out_size, void* d_ws, size_t ws_size,
                              hipStream_t stream)
{
    const float* x = (const float*)d_in[0];
    const float* w = (const float*)d_in[1];
    float* out = (float*)d_out;

    float* ws = (float*)d_ws;
    float* xth    = ws;                                   // RR*BB*4 f32 slots (f16 x2)
    float* wh     = xth + (size_t)RR * BB * 4;            // CC*RR*64 f32 slots
    float* zbase  = wh + (size_t)CC * RR * 64;            // zeroed region:
    float* acc0   = zbase;                                //   ACCW
    float* acc1   = acc0 + ACCW;                          //   ACCW
    float* acc2   = acc1 + ACCW;                          //   ACCW
    float* z1     = acc2 + ACCW;                          //   ZW
    float* z2     = z1 + ZW;                              //   ZW
    unsigned* cnt = (unsigned*)(z2 + ZW);                 //   8 words
    float* v0     = zbase + ZWORDS;                       // CC*BB*OO (fully written)
    float* outsum = v0 + CC * BB * OO;                    // CC*BB*OO

    int4* xth4 = (int4*)xth;
    int4* wh4  = (int4*)wh;
    const float4* w4 = (const float4*)w;

    prep_kernel<<<dim3(432 + 1080), dim3(256), 0, stream>>>(x, xth4, w4, wh4, zbase);
    fused_kernel<<<dim3(NBLK), dim3(256), 0, stream>>>(
        xth4, wh4, acc0, acc1, acc2, z1, z2, v0, outsum, out, cnt);
}

// Round 9
// 155.550 us; speedup vs baseline: 1.7468x; 1.7468x over previous
//
#include <hip/hip_runtime.h>
#include <math.h>

#define BB 64
#define RR 6912
#define II 8
#define CC 10
#define OO 16
#define RPB2 96         // routes per block (fused kernel)
#define NCH2 72         // RR / RPB2
#define NG2 12          // 2-route MFMA groups per wave (24 routes/wave x 4 waves)
#define NBLK 720        // CC * NCH2
#define NREP 9          // accumulator replicas (chunk % NREP)
#define MRG_PAD 20
#define WTILE_I4 (RPB2*16)                 // 1536 int4 = 24 KB W tile
#define MRGF (4*64*MRG_PAD + 4*64)         // 5376 floats merge scratch
#define ACCW (CC*NREP*BB*OO)               // 92160 f32 per iteration
#define ZW   (CC*NREP*BB)                  // 5760 f32
#define BARI (64 + NCH2*32 + NCH2*32)      // barrier ints: gArr/gEp + chArr + chEp
#define ZWORDS (3*ACCW + 2*ZW + BARI)      // zeroed region (floats incl. bar ints)

typedef _Float16 h2 __attribute__((ext_vector_type(2)));
typedef _Float16 half8 __attribute__((ext_vector_type(8)));
typedef float f32x16 __attribute__((ext_vector_type(16)));
union HV { int4 v; h2 h[4]; half8 h8; };

// Returning atomic add: RMW executes AT the coherent point; keeping the return
// live forces the returning encoding, so vmcnt drain == global visibility.
// (R3/R7 precedent: RMW handoff is correct; write-through stores were not.)
__device__ __forceinline__ void addf(float* p, float v) {
    float old = __hip_atomic_fetch_add(p, v, __ATOMIC_RELAXED, __HIP_MEMORY_SCOPE_AGENT);
    asm volatile("" :: "v"(old));
}
__device__ __forceinline__ void addi(int* p) {
    int old = __hip_atomic_fetch_add(p, 1, __ATOMIC_RELAXED, __HIP_MEMORY_SCOPE_AGENT);
    asm volatile("" :: "v"(old));
}
__device__ __forceinline__ void xchi(int* p, int v) {
    int old = __hip_atomic_exchange(p, v, __ATOMIC_RELAXED, __HIP_MEMORY_SCOPE_AGENT);
    asm volatile("" :: "v"(old));
}
// SLP must be a compile-time constant (s_sleep takes a literal immediate —
// R8 compile failure). GUARD bounds the poll so rocprof kernel-replay with
// stale counters falls through instead of hanging.
template <int SLP, int GUARD>
__device__ __forceinline__ void pollge(const int* p, int tgt) {
    int v = __hip_atomic_load(p, __ATOMIC_RELAXED, __HIP_MEMORY_SCOPE_AGENT);
    int g = 0;
    while (v < tgt && ++g < GUARD) {
        __builtin_amdgcn_s_sleep(SLP);
        v = __hip_atomic_load(p, __ATOMIC_RELAXED, __HIP_MEMORY_SCOPE_AGENT);
    }
}

// Hierarchical grid barrier (R7 post-mortem: flat barrier = 720 pollers on ONE
// line; MALL serializes same-line atomics ~110cy -> ~33us/barrier sweep).
// 3 levels, max 72 pollers on any line:
//   arrive: chunk line (10 adds) -> chunk leader -> global line (72 adds)
//   release: global leader sets gEp (71 pollers) -> leaders set chEp (9 pollers)
// All counters monotonic (phase-scaled targets) -> no reset inside the kernel;
// prep zeroes them each launch.
// bar layout (128B-strided lines): [0]=gArr, [32]=gEp, [64+k*32]=chArr[k],
// [64+NCH2*32+k*32]=chEp[k].
__device__ __forceinline__ void gbar(int* bar, int chunk, int c, int phase) {
    __syncthreads();   // drain all waves' data-RMW acks (vmcnt) before arrival
    if (threadIdx.x == 0) {
        int* charr = bar + 64 + chunk * 32;
        int* chep  = bar + 64 + NCH2 * 32 + chunk * 32;
        addi(charr);
        if (c == 0) {                    // chunk leader
            pollge<4, (1 << 14)>(charr, 10 * phase);
            addi(bar + 0);
            if (chunk == 0) {            // global leader
                pollge<8, (1 << 14)>(bar + 0, NCH2 * phase);
                xchi(bar + 32, phase);
            } else {
                pollge<32, (1 << 12)>(bar + 32, phase);
            }
            xchi(chep, phase);
        } else {
            pollge<8, (1 << 13)>(chep, phase);
        }
    }
    __syncthreads();
}

// ---------------- prep kernel ----------------
// blocks [0,432): transpose+cvt x[B][R][8] f32 -> xth[R][B][8] f16
// blocks [432,1512): W convert W[c][r][i][o] f32 -> wh[c][r][o][i] f16
// all blocks: zero a strided slice of the acc/z/barrier region.
__global__ __launch_bounds__(256) void prep_kernel(
    const float* __restrict__ x, int4* __restrict__ xth4,
    const float4* __restrict__ w4, int4* __restrict__ wh4,
    float* __restrict__ zbase)
{
    __shared__ __align__(16) float4 lds4[64 * 34];
    const int t = threadIdx.x;
    const int bid = blockIdx.x;

    for (unsigned idx = (unsigned)bid * 256u + (unsigned)t; idx < (unsigned)ZWORDS;
         idx += 1512u * 256u)
        zbase[idx] = 0.f;

    if (bid < 432) {
        const int rblk = bid >> 2;
        const int bblk = bid & 3;
        const int r0 = rblk * 64, b0 = bblk * 16;
        {
            const int rl = t & 63;
            const int bl0 = t >> 6;
#pragma unroll
            for (int kb = 0; kb < 4; ++kb) {
                const int bl = kb * 4 + bl0;
                const float4* src = (const float4*)(x + ((size_t)(b0 + bl) * RR + (r0 + rl)) * II);
                lds4[rl * 34 + bl * 2 + 0] = src[0];
                lds4[rl * 34 + bl * 2 + 1] = src[1];
            }
        }
        __syncthreads();
        {
            const int bl = t & 15;
            const int rw0 = t >> 4;
#pragma unroll
            for (int kr = 0; kr < 4; ++kr) {
                const int rw = kr * 16 + rw0;
                float4 a = lds4[rw * 34 + bl * 2 + 0];
                float4 bq = lds4[rw * 34 + bl * 2 + 1];
                HV u;
                u.h[0] = h2{(_Float16)a.x,  (_Float16)a.y};
                u.h[1] = h2{(_Float16)a.z,  (_Float16)a.w};
                u.h[2] = h2{(_Float16)bq.x, (_Float16)bq.y};
                u.h[3] = h2{(_Float16)bq.z, (_Float16)bq.w};
                xth4[(size_t)(r0 + rw) * BB + (b0 + bl)] = u.v;
            }
        }
    } else {
        _Float16* wl = (_Float16*)lds4;
        const int wblk = bid - 432;          // 0..1079
        const int rp = t >> 5;
        const int i  = (t >> 2) & 7;
        const int o0 = (t & 3) * 4;
#pragma unroll 1
        for (int sb = 0; sb < 8; ++sb) {
            const int blk8 = wblk * 8 + sb;  // == c*864 + (r/8)
            const float4 v = w4[(size_t)blk8 * 256 + t];
            _Float16* wb = wl + (sb & 1) * 1024;
            wb[(rp * 16 + o0 + 0) * 8 + i] = (_Float16)v.x;
            wb[(rp * 16 + o0 + 1) * 8 + i] = (_Float16)v.y;
            wb[(rp * 16 + o0 + 2) * 8 + i] = (_Float16)v.z;
            wb[(rp * 16 + o0 + 3) * 8 + i] = (_Float16)v.w;
            __syncthreads();
            if (t < 128) wh4[(size_t)blk8 * 128 + t] = ((const int4*)wb)[t];
        }
    }
}

// ---------------- routing iteration (identical to R7, which passed) ----------------
template <int MODE>
__device__ __forceinline__ void it_phase(
    const int4* __restrict__ xth4, const int4* wlds, float* mrg,
    const float* __restrict__ ov,
    float* __restrict__ acc, float* __restrict__ zacc,
    int c, int chunk, int t)
{
    const int wv = t >> 6;
    const int l = t & 63;
    const int b = l & 31;
    const int hi = l >> 5;
    const int aquad = (l >> 4) & 1;
    const bool aact = (aquad == hi);

    float accA[8], accB[8];
#pragma unroll
    for (int j = 0; j < 8; ++j) { accA[j] = 0.f; accB[j] = 0.f; }
    float ZA = 0.f, ZB = 0.f;

    float ovA[8], ovB[8];
    if (MODE != 0) {
        const float* pa = ov + ((size_t)c * BB + b) * OO + 4 * hi;
        const float* pb = ov + ((size_t)c * BB + 32 + b) * OO + 4 * hi;
        float4 a0 = *(const float4*)(pa);
        float4 a1 = *(const float4*)(pa + 8);
        float4 b0 = *(const float4*)(pb);
        float4 b1 = *(const float4*)(pb + 8);
        ovA[0]=a0.x; ovA[1]=a0.y; ovA[2]=a0.z; ovA[3]=a0.w;
        ovA[4]=a1.x; ovA[5]=a1.y; ovA[6]=a1.z; ovA[7]=a1.w;
        ovB[0]=b0.x; ovB[1]=b0.y; ovB[2]=b0.z; ovB[3]=b0.w;
        ovB[4]=b1.x; ovB[5]=b1.y; ovB[6]=b1.z; ovB[7]=b1.w;
    }

    const int rbase = chunk * RPB2 + wv * 24;

    f32x16 cA, cB, zf;
#pragma unroll
    for (int q = 0; q < 16; ++q) { cA[q] = 0.f; cB[q] = 0.f; zf[q] = 0.f; }

    HV xc0, xc1, xn0, xn1;
    xc0.v = xth4[(size_t)(rbase + hi) * BB + b];
    xc1.v = xth4[(size_t)(rbase + hi) * BB + 32 + b];
    xn0 = xc0; xn1 = xc1;

#pragma unroll 1
    for (int g = 0; g < NG2; ++g) {
        if (g + 1 < NG2) {
            const int rn = rbase + (g + 1) * 2 + hi;
            xn0.v = xth4[(size_t)rn * BB + b];
            xn1.v = xth4[(size_t)rn * BB + 32 + b];
        }
        const int rl0 = wv * 24 + g * 2;
        HV wq;
        wq.v = wlds[(rl0 + aquad) * 16 + (l & 15)];
        if (!aact) wq.v = make_int4(0, 0, 0, 0);

        if (MODE == 0) {
            cA = __builtin_amdgcn_mfma_f32_32x32x16_f16(wq.h8, xc0.h8, cA, 0, 0, 0);
            cB = __builtin_amdgcn_mfma_f32_32x32x16_f16(wq.h8, xc1.h8, cB, 0, 0, 0);
        } else {
            f32x16 p0 = __builtin_amdgcn_mfma_f32_32x32x16_f16(wq.h8, xc0.h8, zf, 0, 0, 0);
            f32x16 p1 = __builtin_amdgcn_mfma_f32_32x32x16_f16(wq.h8, xc1.h8, zf, 0, 0, 0);
            float dA0 = 0.f, dA1 = 0.f, dB0 = 0.f, dB1 = 0.f;
#pragma unroll
            for (int j = 0; j < 8; ++j) {
                dA0 = fmaf(p0[j],     ovA[j], dA0);
                dA1 = fmaf(p0[j + 8], ovA[j], dA1);
                dB0 = fmaf(p1[j],     ovB[j], dB0);
                dB1 = fmaf(p1[j + 8], ovB[j], dB1);
            }
            dA0 += __shfl_xor(dA0, 32);
            dA1 += __shfl_xor(dA1, 32);
            dB0 += __shfl_xor(dB0, 32);
            dB1 += __shfl_xor(dB1, 32);
            const float eA0 = __expf(dA0), eA1 = __expf(dA1);
            const float eB0 = __expf(dB0), eB1 = __expf(dB1);
            ZA += eA0 + eA1; ZB += eB0 + eB1;
#pragma unroll
            for (int j = 0; j < 8; ++j) {
                accA[j] = fmaf(eA0, p0[j], fmaf(eA1, p0[j + 8], accA[j]));
                accB[j] = fmaf(eB0, p1[j], fmaf(eB1, p1[j + 8], accB[j]));
            }
        }
        xc0 = xn0; xc1 = xn1;
    }

    if (MODE == 0) {
#pragma unroll
        for (int j = 0; j < 8; ++j) {
            accA[j] = cA[j] + cA[j + 8];
            accB[j] = cB[j] + cB[j + 8];
        }
    }

    {
        float* m0 = mrg + (wv * 64 + b) * MRG_PAD + 4 * hi;
        *(float4*)(m0)     = make_float4(accA[0], accA[1], accA[2], accA[3]);
        *(float4*)(m0 + 8) = make_float4(accA[4], accA[5], accA[6], accA[7]);
        float* m1 = mrg + (wv * 64 + 32 + b) * MRG_PAD + 4 * hi;
        *(float4*)(m1)     = make_float4(accB[0], accB[1], accB[2], accB[3]);
        *(float4*)(m1 + 8) = make_float4(accB[4], accB[5], accB[6], accB[7]);
        if (MODE != 0 && hi == 0) {
            float* zr = mrg + 4 * 64 * MRG_PAD;
            zr[wv * 64 + b] = ZA;
            zr[wv * 64 + 32 + b] = ZB;
        }
    }
    __syncthreads();

    {
        const int b2 = t >> 2, q = t & 3;
        float4 sum = make_float4(0.f, 0.f, 0.f, 0.f);
#pragma unroll
        for (int w2 = 0; w2 < 4; ++w2) {
            const float4 v = *(const float4*)(mrg + (w2 * 64 + b2) * MRG_PAD + q * 4);
            sum.x += v.x; sum.y += v.y; sum.z += v.z; sum.w += v.w;
        }
        const int rep = chunk % NREP;
        float* dst = acc + (((size_t)c * NREP + rep) * BB + b2) * OO + q * 4;
        addf(dst + 0, sum.x);
        addf(dst + 1, sum.y);
        addf(dst + 2, sum.z);
        addf(dst + 3, sum.w);
        if (MODE != 0 && q == 0) {
            const float* zr = mrg + 4 * 64 * MRG_PAD;
            float z = 0.f;
#pragma unroll
            for (int w2 = 0; w2 < 4; ++w2) z += zr[w2 * 64 + b2];
            addf(zacc + ((size_t)c * NREP + rep) * BB + b2, z);
        }
    }
}

// ---------------- combine (identical to R7, which passed) ----------------
template <int MODE>
__device__ __forceinline__ void combine_phase(
    const float* __restrict__ acc, const float* __restrict__ zacc,
    const float* __restrict__ addv, float* __restrict__ dst, bool coh,
    int bid, int t, float* cl)
{
    const int c2 = bid >> 6, b2 = bid & 63;
    const int o = t & 15, g = t >> 4;

    float s = (g < NREP) ? acc[(((size_t)c2 * NREP + g) * BB + b2) * OO + o] : 0.f;
    cl[t] = s;
    if (MODE != 0 && o == 0)
        cl[256 + g] = (g < NREP) ? zacc[((size_t)c2 * NREP + g) * BB + b2] : 0.f;
    __syncthreads();

    if (g == 0) {
#pragma unroll
        for (int k = 1; k < NREP; ++k) s += cl[k * 16 + o];
        if (MODE != 0) {
            float Zt = 0.f;
#pragma unroll
            for (int k = 0; k < NREP; ++k) Zt += cl[256 + k];
            s /= Zt;
        } else {
            s *= (1.0f / RR);
        }
        float sq = s * s;
#pragma unroll
        for (int w = 1; w < 16; w <<= 1) sq += __shfl_xor(sq, w);
        float val = s * sqrtf(sq) / (1.f + sq);
        if (MODE == 1) val += addv[(size_t)bid * OO + o];
        if (coh) {
            float old = __hip_atomic_exchange(dst + (size_t)bid * OO + o, val,
                         __ATOMIC_RELAXED, __HIP_MEMORY_SCOPE_AGENT);
            asm volatile("" :: "v"(old));
        } else {
            dst[(size_t)bid * OO + o] = val;   // final output: dispatch-end flush
        }
    }
    __syncthreads();
}

// ---------------- fused routing kernel ----------------
// 720 blocks co-resident (LDS 47.6KB -> 3 blocks/CU; capacity 768). W staged
// once. XCD-bijective swizzle u=(bid&7)*90+(bid>>3): 720=8*90 and 90%10==0, so
// all 10 c-blocks of a chunk share bid&7 (one XCD) -> x reads L2-hit instead
// of 8x HBM re-fetch (R7: FETCH 93MB, all-miss). Barriers hierarchical (see
// gbar). All cross-block handoff via returning RMWs (R7-proven correct).
__global__ __launch_bounds__(256, 3) void fused_kernel(
    const int4* __restrict__ xth4, const int4* __restrict__ wh4,
    float* acc0, float* acc1, float* acc2, float* z1, float* z2,
    float* v0, float* outsum, float* out, int* bar)
{
    __shared__ __align__(16) int4 wlds[WTILE_I4];   // 24576 B
    __shared__ __align__(16) float mrg[MRGF];       // 21504 B
    __shared__ float cl[272];                       //  1088 B

    const int bid = blockIdx.x;
    const int t = threadIdx.x;
    const int u = (bid & 7) * 90 + (bid >> 3);
    const int chunk = u / 10;
    const int c = u - chunk * 10;

    {
        const int4* src = wh4 + ((size_t)c * RR + (size_t)chunk * RPB2) * 16;
#pragma unroll
        for (int k = 0; k < 6; ++k) wlds[k * 256 + t] = src[k * 256 + t];
    }
    __syncthreads();

    it_phase<0>(xth4, wlds, mrg, nullptr, acc0, nullptr, c, chunk, t);
    gbar(bar, chunk, c, 1);
    if (bid < CC * BB) combine_phase<0>(acc0, nullptr, nullptr, v0, true, bid, t, cl);
    gbar(bar, chunk, c, 2);
    it_phase<1>(xth4, wlds, mrg, v0, acc1, z1, c, chunk, t);
    gbar(bar, chunk, c, 3);
    if (bid < CC * BB) combine_phase<1>(acc1, z1, v0, outsum, true, bid, t, cl);
    gbar(bar, chunk, c, 4);
    it_phase<2>(xth4, wlds, mrg, outsum, acc2, z2, c, chunk, t);
    gbar(bar, chunk, c, 5);
    if (bid < CC * BB) combine_phase<2>(acc2, z2, nullptr, out, false, bid, t, cl);
}

extern "C" void kernel_launch(void* const* d_in, const int* in_sizes, int n_in,
                              void* d_out, int out_size, void* d_ws, size_t ws_size,
                              hipStream_t stream)
{
    const float* x = (const float*)d_in[0];
    const float* w = (const float*)d_in[1];
    float* out = (float*)d_out;

    float* ws = (float*)d_ws;
    float* xth    = ws;                                   // RR*BB*4 f32 slots (f16 x2)
    float* wh     = xth + (size_t)RR * BB * 4;            // CC*RR*64 f32 slots
    float* zbase  = wh + (size_t)CC * RR * 64;            // zeroed region:
    float* acc0   = zbase;                                //   ACCW
    float* acc1   = acc0 + ACCW;                          //   ACCW
    float* acc2   = acc1 + ACCW;                          //   ACCW
    float* z1     = acc2 + ACCW;                          //   ZW
    float* z2     = z1 + ZW;                              //   ZW
    int*   bar    = (int*)(z2 + ZW);                      //   BARI ints
    float* v0     = zbase + ZWORDS;                       // CC*BB*OO
    float* outsum = v0 + CC * BB * OO;                    // CC*BB*OO

    int4* xth4 = (int4*)xth;
    int4* wh4  = (int4*)wh;
    const float4* w4 = (const float4*)w;

    prep_kernel<<<dim3(432 + 1080), dim3(256), 0, stream>>>(x, xth4, w4, wh4, zbase);
    fused_kernel<<<dim3(NBLK), dim3(256), 0, stream>>>(
        xth4, wh4, acc0, acc1, acc2, z1, z2, v0, outsum, out, bar);
}

// Round 10
// 141.629 us; speedup vs baseline: 1.9185x; 1.0983x over previous
//
#include <hip/hip_runtime.h>
#include <math.h>

#define BB 64
#define RR 6912
#define II 8
#define CC 10
#define OO 16
#define RPB2 96         // routes per block (fused kernel)
#define NCH2 72         // RR / RPB2
#define NG2 12          // 2-route MFMA groups per wave (24 routes/wave x 4 waves)
#define NBLK 720        // CC * NCH2
#define MRG_PAD 20
#define WTILE_I4 (RPB2*16)                 // 1536 int4 = 24 KB W tile
#define MRGF (4*64*MRG_PAD + 4*64)         // 5376 floats merge scratch
#define PWW (CC*NCH2*BB*OO)                // per-iteration partials (737280 f32)
#define PZW (CC*NCH2*BB)                   // 46080 f32
// flag lines (128B-strided): arrCnt[c], arrRep[c][8], cdone[c], rdone[c][8]
#define L_ARR(c)      ((c) * 32)
#define L_ARREP(c,r)  ((10 + (c)*8 + (r)) * 32)
#define L_CD(c)       ((90 + (c)) * 32)
#define L_RD(c,r)     ((100 + (c)*8 + (r)) * 32)
#define FLAGI (180*32)

typedef _Float16 h2 __attribute__((ext_vector_type(2)));
typedef _Float16 half8 __attribute__((ext_vector_type(8)));
typedef float f32x16 __attribute__((ext_vector_type(16)));
union HV { int4 v; h2 h[4]; half8 h8; };

// Returning atomics: RMW executes AT the coherent point; keeping the return
// live forces the returning encoding, so vmcnt drain == global visibility
// (R3/R7/R9-proven). Exchanges to UNIQUE addresses give the visibility
// guarantee with zero line contention (R9 post-mortem: contended atomicAdd
// replicas serialized ~250 RMWs/line at the MALL).
__device__ __forceinline__ void xchf(float* p, float v) {
    float old = __hip_atomic_exchange(p, v, __ATOMIC_RELAXED, __HIP_MEMORY_SCOPE_AGENT);
    asm volatile("" :: "v"(old));
}
__device__ __forceinline__ void xchf2(float* p, float a, float b) {
    union { unsigned long long u; float f[2]; } v;
    v.f[0] = a; v.f[1] = b;
    unsigned long long old = __hip_atomic_exchange((unsigned long long*)p, v.u,
                              __ATOMIC_RELAXED, __HIP_MEMORY_SCOPE_AGENT);
    asm volatile("" :: "v"(old));
}
__device__ __forceinline__ int addi(int* p) {
    return __hip_atomic_fetch_add(p, 1, __ATOMIC_RELAXED, __HIP_MEMORY_SCOPE_AGENT);
}
__device__ __forceinline__ void xchi(int* p, int v) {
    int old = __hip_atomic_exchange(p, v, __ATOMIC_RELAXED, __HIP_MEMORY_SCOPE_AGENT);
    asm volatile("" :: "v"(old));
}
// SLP is a compile-time literal (s_sleep immediate). GUARD bounds the poll so
// rocprof kernel-replay with stale (monotonic) flags falls through instantly.
template <int SLP, int GUARD>
__device__ __forceinline__ void pollge(const int* p, int tgt) {
    int v = __hip_atomic_load(p, __ATOMIC_RELAXED, __HIP_MEMORY_SCOPE_AGENT);
    int g = 0;
    while (v < tgt && ++g < GUARD) {
        __builtin_amdgcn_s_sleep(SLP);
        v = __hip_atomic_load(p, __ATOMIC_RELAXED, __HIP_MEMORY_SCOPE_AGENT);
    }
}

// ---------------- prep kernel ----------------
// blocks [0,432): transpose+cvt x[B][R][8] f32 -> xth[R][B][8] f16
// blocks [432,1512): W convert W[c][r][i][o] f32 -> wh[c][r][o][i] f16
// all blocks: zero a slice of the (tiny, 23KB) flag region.
__global__ __launch_bounds__(256) void prep_kernel(
    const float* __restrict__ x, int4* __restrict__ xth4,
    const float4* __restrict__ w4, int4* __restrict__ wh4,
    int* __restrict__ flags)
{
    __shared__ __align__(16) float4 lds4[64 * 34];
    const int t = threadIdx.x;
    const int bid = blockIdx.x;

    {
        const unsigned idx = (unsigned)bid * 256u + (unsigned)t;
        if (idx < (unsigned)FLAGI) flags[idx] = 0;
    }

    if (bid < 432) {
        const int rblk = bid >> 2;
        const int bblk = bid & 3;
        const int r0 = rblk * 64, b0 = bblk * 16;
        {
            const int rl = t & 63;
            const int bl0 = t >> 6;
#pragma unroll
            for (int kb = 0; kb < 4; ++kb) {
                const int bl = kb * 4 + bl0;
                const float4* src = (const float4*)(x + ((size_t)(b0 + bl) * RR + (r0 + rl)) * II);
                lds4[rl * 34 + bl * 2 + 0] = src[0];
                lds4[rl * 34 + bl * 2 + 1] = src[1];
            }
        }
        __syncthreads();
        {
            const int bl = t & 15;
            const int rw0 = t >> 4;
#pragma unroll
            for (int kr = 0; kr < 4; ++kr) {
                const int rw = kr * 16 + rw0;
                float4 a = lds4[rw * 34 + bl * 2 + 0];
                float4 bq = lds4[rw * 34 + bl * 2 + 1];
                HV u;
                u.h[0] = h2{(_Float16)a.x,  (_Float16)a.y};
                u.h[1] = h2{(_Float16)a.z,  (_Float16)a.w};
                u.h[2] = h2{(_Float16)bq.x, (_Float16)bq.y};
                u.h[3] = h2{(_Float16)bq.z, (_Float16)bq.w};
                xth4[(size_t)(r0 + rw) * BB + (b0 + bl)] = u.v;
            }
        }
    } else {
        _Float16* wl = (_Float16*)lds4;
        const int wblk = bid - 432;          // 0..1079
        const int rp = t >> 5;
        const int i  = (t >> 2) & 7;
        const int o0 = (t & 3) * 4;
#pragma unroll 1
        for (int sb = 0; sb < 8; ++sb) {
            const int blk8 = wblk * 8 + sb;  // == c*864 + (r/8)
            const float4 v = w4[(size_t)blk8 * 256 + t];
            _Float16* wb = wl + (sb & 1) * 1024;
            wb[(rp * 16 + o0 + 0) * 8 + i] = (_Float16)v.x;
            wb[(rp * 16 + o0 + 1) * 8 + i] = (_Float16)v.y;
            wb[(rp * 16 + o0 + 2) * 8 + i] = (_Float16)v.z;
            wb[(rp * 16 + o0 + 3) * 8 + i] = (_Float16)v.w;
            __syncthreads();
            if (t < 128) wh4[(size_t)blk8 * 128 + t] = ((const int4*)wb)[t];
        }
    }
}

// ---------------- routing iteration ----------------
// MFMA core identical to R7/R9 (passed). ph = iteration index + 1.
// Entry (MODE!=0): poll rdone[c][xcd] >= ph-1 (<=9 pollers/line), then load ov.
// Exit: per-chunk UNIQUE-address exchanges (no contention), syncthreads
// (drain acks), arrival add; last arriver broadcasts 8 arrRep replicas.
template <int MODE>
__device__ __forceinline__ void it_phase(
    const int4* __restrict__ xth4, const int4* wlds, float* mrg,
    const float* __restrict__ ov,
    float* __restrict__ pw, float* __restrict__ pz,
    int* flags, int c, int chunk, int xcd, int t, int ph)
{
    const int wv = t >> 6;
    const int l = t & 63;
    const int b = l & 31;
    const int hi = l >> 5;
    const int aquad = (l >> 4) & 1;
    const bool aact = (aquad == hi);

    if (MODE != 0) {
        if (t == 0) pollge<8, (1 << 14)>(flags + L_RD(c, xcd), ph - 1);
        __syncthreads();   // compiler+exec fence: ov loads stay below the poll
    }

    float accA[8], accB[8];
#pragma unroll
    for (int j = 0; j < 8; ++j) { accA[j] = 0.f; accB[j] = 0.f; }
    float ZA = 0.f, ZB = 0.f;

    float ovA[8], ovB[8];
    if (MODE != 0) {
        const float* pa = ov + ((size_t)c * BB + b) * OO + 4 * hi;
        const float* pb = ov + ((size_t)c * BB + 32 + b) * OO + 4 * hi;
        float4 a0 = *(const float4*)(pa);
        float4 a1 = *(const float4*)(pa + 8);
        float4 b0 = *(const float4*)(pb);
        float4 b1 = *(const float4*)(pb + 8);
        ovA[0]=a0.x; ovA[1]=a0.y; ovA[2]=a0.z; ovA[3]=a0.w;
        ovA[4]=a1.x; ovA[5]=a1.y; ovA[6]=a1.z; ovA[7]=a1.w;
        ovB[0]=b0.x; ovB[1]=b0.y; ovB[2]=b0.z; ovB[3]=b0.w;
        ovB[4]=b1.x; ovB[5]=b1.y; ovB[6]=b1.z; ovB[7]=b1.w;
    }

    const int rbase = chunk * RPB2 + wv * 24;

    f32x16 cA, cB, zf;
#pragma unroll
    for (int q = 0; q < 16; ++q) { cA[q] = 0.f; cB[q] = 0.f; zf[q] = 0.f; }

    HV xc0, xc1, xn0, xn1;
    xc0.v = xth4[(size_t)(rbase + hi) * BB + b];
    xc1.v = xth4[(size_t)(rbase + hi) * BB + 32 + b];
    xn0 = xc0; xn1 = xc1;

#pragma unroll 1
    for (int g = 0; g < NG2; ++g) {
        if (g + 1 < NG2) {
            const int rn = rbase + (g + 1) * 2 + hi;
            xn0.v = xth4[(size_t)rn * BB + b];
            xn1.v = xth4[(size_t)rn * BB + 32 + b];
        }
        const int rl0 = wv * 24 + g * 2;
        HV wq;
        wq.v = wlds[(rl0 + aquad) * 16 + (l & 15)];
        if (!aact) wq.v = make_int4(0, 0, 0, 0);

        if (MODE == 0) {
            cA = __builtin_amdgcn_mfma_f32_32x32x16_f16(wq.h8, xc0.h8, cA, 0, 0, 0);
            cB = __builtin_amdgcn_mfma_f32_32x32x16_f16(wq.h8, xc1.h8, cB, 0, 0, 0);
        } else {
            f32x16 p0 = __builtin_amdgcn_mfma_f32_32x32x16_f16(wq.h8, xc0.h8, zf, 0, 0, 0);
            f32x16 p1 = __builtin_amdgcn_mfma_f32_32x32x16_f16(wq.h8, xc1.h8, zf, 0, 0, 0);
            float dA0 = 0.f, dA1 = 0.f, dB0 = 0.f, dB1 = 0.f;
#pragma unroll
            for (int j = 0; j < 8; ++j) {
                dA0 = fmaf(p0[j],     ovA[j], dA0);
                dA1 = fmaf(p0[j + 8], ovA[j], dA1);
                dB0 = fmaf(p1[j],     ovB[j], dB0);
                dB1 = fmaf(p1[j + 8], ovB[j], dB1);
            }
            dA0 += __shfl_xor(dA0, 32);
            dA1 += __shfl_xor(dA1, 32);
            dB0 += __shfl_xor(dB0, 32);
            dB1 += __shfl_xor(dB1, 32);
            const float eA0 = __expf(dA0), eA1 = __expf(dA1);
            const float eB0 = __expf(dB0), eB1 = __expf(dB1);
            ZA += eA0 + eA1; ZB += eB0 + eB1;
#pragma unroll
            for (int j = 0; j < 8; ++j) {
                accA[j] = fmaf(eA0, p0[j], fmaf(eA1, p0[j + 8], accA[j]));
                accB[j] = fmaf(eB0, p1[j], fmaf(eB1, p1[j + 8], accB[j]));
            }
        }
        xc0 = xn0; xc1 = xn1;
    }

    if (MODE == 0) {
#pragma unroll
        for (int j = 0; j < 8; ++j) {
            accA[j] = cA[j] + cA[j + 8];
            accB[j] = cB[j] + cB[j + 8];
        }
    }

    {
        float* m0 = mrg + (wv * 64 + b) * MRG_PAD + 4 * hi;
        *(float4*)(m0)     = make_float4(accA[0], accA[1], accA[2], accA[3]);
        *(float4*)(m0 + 8) = make_float4(accA[4], accA[5], accA[6], accA[7]);
        float* m1 = mrg + (wv * 64 + 32 + b) * MRG_PAD + 4 * hi;
        *(float4*)(m1)     = make_float4(accB[0], accB[1], accB[2], accB[3]);
        *(float4*)(m1 + 8) = make_float4(accB[4], accB[5], accB[6], accB[7]);
        if (MODE != 0 && hi == 0) {
            float* zr = mrg + 4 * 64 * MRG_PAD;
            zr[wv * 64 + b] = ZA;
            zr[wv * 64 + 32 + b] = ZB;
        }
    }
    __syncthreads();

    // block partial -> unique per-chunk slots (returning 64-bit exchanges)
    {
        const int b2 = t >> 2, q = t & 3;
        float4 sum = make_float4(0.f, 0.f, 0.f, 0.f);
#pragma unroll
        for (int w2 = 0; w2 < 4; ++w2) {
            const float4 v = *(const float4*)(mrg + (w2 * 64 + b2) * MRG_PAD + q * 4);
            sum.x += v.x; sum.y += v.y; sum.z += v.z; sum.w += v.w;
        }
        float* dst = pw + (((size_t)(c * NCH2 + chunk) * BB + b2) * OO) + q * 4;
        xchf2(dst + 0, sum.x, sum.y);
        xchf2(dst + 2, sum.z, sum.w);
        if (MODE != 0 && q == 0) {
            const float* zr = mrg + 4 * 64 * MRG_PAD;
            float z = 0.f;
#pragma unroll
            for (int w2 = 0; w2 < 4; ++w2) z += zr[w2 * 64 + b2];
            xchf(pz + (size_t)(c * NCH2 + chunk) * BB + b2, z);
        }
    }

    __syncthreads();   // drain exchange acks (vmcnt) before arrival
    if (t == 0) {
        const int old = addi(flags + L_ARR(c));
        if (old == NCH2 * ph - 1) {
#pragma unroll
            for (int r = 0; r < 8; ++r) xchi(flags + L_ARREP(c, r), ph);
        }
    }
}

// ---------------- combine: block (c2,b2)=bid sums 72 chunk partials + squash ----------------
template <int MODE>
__device__ __forceinline__ void combine_phase(
    const float* __restrict__ pw, const float* __restrict__ pzw,
    const float* __restrict__ addv, float* __restrict__ dst, bool coh,
    int* flags, int bid, int t, float* cl, int ph)
{
    const int c2 = bid >> 6, b2 = bid & 63;
    const int o = t & 15, g = t >> 4;

    if (t == 0) pollge<8, (1 << 14)>(flags + L_ARREP(c2, bid & 7), ph);
    __syncthreads();   // fence: partial loads stay below the poll

    const float* base = pw + (size_t)c2 * NCH2 * (BB * OO);
    float s = 0.f, zl = 0.f;
#pragma unroll
    for (int k = 0; k < 5; ++k) {
        const int rid = g + k * 16;
        if (rid < NCH2) {
            s += base[(size_t)rid * (BB * OO) + b2 * OO + o];
            if (MODE != 0 && o == 0)
                zl += pzw[(size_t)c2 * NCH2 * BB + (size_t)rid * BB + b2];
        }
    }
    cl[t] = s;
    if (MODE != 0 && o == 0) cl[256 + g] = zl;
    __syncthreads();

    if (g == 0) {
#pragma unroll
        for (int k = 1; k < 16; ++k) s += cl[k * 16 + o];
        if (MODE != 0) {
            float Zt = 0.f;
#pragma unroll
            for (int k = 0; k < 16; ++k) Zt += cl[256 + k];
            s /= Zt;
        } else {
            s *= (1.0f / RR);
        }
        float sq = s * s;
#pragma unroll
        for (int w = 1; w < 16; w <<= 1) sq += __shfl_xor(sq, w);
        float val = s * sqrtf(sq) / (1.f + sq);
        if (MODE == 1) val += addv[(size_t)bid * OO + o];
        if (coh) xchf(dst + (size_t)bid * OO + o, val);
        else     dst[(size_t)bid * OO + o] = val;   // final out: dispatch-end flush
    }
    __syncthreads();   // drain v-write acks before completion count

    if (MODE != 2 && t == 0) {
        const int old = addi(flags + L_CD(c2));
        if (old == CC * BB / CC * ph - 1) {      // 64 combine blocks per class
#pragma unroll
            for (int r = 0; r < 8; ++r) xchi(flags + L_RD(c2, r), ph);
        }
    }
}

// ---------------- fused routing kernel ----------------
// 720 blocks co-resident (LDS 47.2KB -> 3/CU, capacity 768). W staged once.
// XCD-bijective swizzle (R9-proven: FETCH 93->14MB). Producer-consumer flags
// replace grid barriers: every polled line has <=9 pollers (R9 post-mortem:
// same-line atomic sweeps serialize ~110cy at the MALL).
__global__ __launch_bounds__(256, 3) void fused_kernel(
    const int4* __restrict__ xth4, const int4* __restrict__ wh4,
    float* pw0, float* pw1, float* pw2, float* pz1, float* pz2,
    float* v0, float* outsum, float* out, int* flags)
{
    __shared__ __align__(16) int4 wlds[WTILE_I4];   // 24576 B
    __shared__ __align__(16) float mrg[MRGF];       // 21504 B
    __shared__ float cl[272];                       //  1088 B

    const int bid = blockIdx.x;
    const int t = threadIdx.x;
    const int xcd = bid & 7;
    const int u = xcd * 90 + (bid >> 3);
    const int chunk = u / 10;
    const int c = u - chunk * 10;

    {
        const int4* src = wh4 + ((size_t)c * RR + (size_t)chunk * RPB2) * 16;
#pragma unroll
        for (int k = 0; k < 6; ++k) wlds[k * 256 + t] = src[k * 256 + t];
    }
    __syncthreads();

    it_phase<0>(xth4, wlds, mrg, nullptr, pw0, nullptr, flags, c, chunk, xcd, t, 1);
    if (bid < CC * BB) combine_phase<0>(pw0, nullptr, nullptr, v0, true, flags, bid, t, cl, 1);
    it_phase<1>(xth4, wlds, mrg, v0, pw1, pz1, flags, c, chunk, xcd, t, 2);
    if (bid < CC * BB) combine_phase<1>(pw1, pz1, v0, outsum, true, flags, bid, t, cl, 2);
    it_phase<2>(xth4, wlds, mrg, outsum, pw2, pz2, flags, c, chunk, xcd, t, 3);
    if (bid < CC * BB) combine_phase<2>(pw2, pz2, nullptr, out, false, flags, bid, t, cl, 3);
}

extern "C" void kernel_launch(void* const* d_in, const int* in_sizes, int n_in,
                              void* d_out, int out_size, void* d_ws, size_t ws_size,
                              hipStream_t stream)
{
    const float* x = (const float*)d_in[0];
    const float* w = (const float*)d_in[1];
    float* out = (float*)d_out;

    float* ws = (float*)d_ws;
    float* xth    = ws;                                   // RR*BB*4 f32 slots (f16 x2)
    float* wh     = xth + (size_t)RR * BB * 4;            // CC*RR*64 f32 slots
    float* pw0    = wh + (size_t)CC * RR * 64;            // PWW
    float* pw1    = pw0 + PWW;                            // PWW
    float* pw2    = pw1 + PWW;                            // PWW
    float* pz1    = pw2 + PWW;                            // PZW
    float* pz2    = pz1 + PZW;                            // PZW
    float* v0     = pz2 + PZW;                            // CC*BB*OO
    float* outsum = v0 + CC * BB * OO;                    // CC*BB*OO
    int*   flags  = (int*)(outsum + CC * BB * OO);        // FLAGI ints

    int4* xth4 = (int4*)xth;
    int4* wh4  = (int4*)wh;
    const float4* w4 = (const float4*)w;

    prep_kernel<<<dim3(432 + 1080), dim3(256), 0, stream>>>(x, xth4, w4, wh4, flags);
    fused_kernel<<<dim3(NBLK), dim3(256), 0, stream>>>(
        xth4, wh4, pw0, pw1, pw2, pz1, pz2, v0, outsum, out, flags);
}

// Round 11
// 133.732 us; speedup vs baseline: 2.0318x; 1.0591x over previous
//
#include <hip/hip_runtime.h>
#include <math.h>

#define BB 64
#define RR 6912
#define II 8
#define CC 10
#define OO 16
#define RPB2 96         // routes per block (fused kernel)
#define NCH2 72         // RR / RPB2
#define NG2 12          // 2-route MFMA groups per wave (24 routes/wave x 4 waves)
#define NBLK 720        // CC * NCH2
#define MRG_PAD 20
#define WTILE_I4 (RPB2*16)                 // 1536 int4 = 24 KB W tile
#define MRGF (4*64*MRG_PAD + 4*64)         // 5376 floats merge scratch
#define PWW (CC*NCH2*BB*OO)                // per-iteration partials (737280 f32)
#define PZW (CC*NCH2*BB)                   // 46080 f32
// flag lines (128B-strided): arrCnt[c], arrRep[c][8], cdone[c], rdone[c][8]
#define L_ARR(c)      ((c) * 32)
#define L_ARREP(c,r)  ((10 + (c)*8 + (r)) * 32)
#define L_CD(c)       ((90 + (c)) * 32)
#define L_RD(c,r)     ((100 + (c)*8 + (r)) * 32)
#define FLAGI (180*32)

typedef _Float16 h2 __attribute__((ext_vector_type(2)));
typedef _Float16 half8 __attribute__((ext_vector_type(8)));
typedef float f32x16 __attribute__((ext_vector_type(16)));
union HV { int4 v; h2 h[4]; half8 h8; };

// Returning atomics: RMW executes AT the coherent point; keeping the return
// live forces the returning encoding, so vmcnt drain == global visibility
// (R3/R7/R9-proven). Exchanges to UNIQUE addresses give the visibility
// guarantee with zero line contention (R9/R10-proven).
__device__ __forceinline__ void xchf(float* p, float v) {
    float old = __hip_atomic_exchange(p, v, __ATOMIC_RELAXED, __HIP_MEMORY_SCOPE_AGENT);
    asm volatile("" :: "v"(old));
}
__device__ __forceinline__ void xchf2(float* p, float a, float b) {
    union { unsigned long long u; float f[2]; } v;
    v.f[0] = a; v.f[1] = b;
    unsigned long long old = __hip_atomic_exchange((unsigned long long*)p, v.u,
                              __ATOMIC_RELAXED, __HIP_MEMORY_SCOPE_AGENT);
    asm volatile("" :: "v"(old));
}
__device__ __forceinline__ int addi(int* p) {
    return __hip_atomic_fetch_add(p, 1, __ATOMIC_RELAXED, __HIP_MEMORY_SCOPE_AGENT);
}
__device__ __forceinline__ void xchi(int* p, int v) {
    int old = __hip_atomic_exchange(p, v, __ATOMIC_RELAXED, __HIP_MEMORY_SCOPE_AGENT);
    asm volatile("" :: "v"(old));
}
// SLP is a compile-time literal (s_sleep immediate — R8 lesson). GUARD bounds
// the poll so rocprof kernel-replay with stale (monotonic) flags falls through.
template <int SLP, int GUARD>
__device__ __forceinline__ void pollge(const int* p, int tgt) {
    int v = __hip_atomic_load(p, __ATOMIC_RELAXED, __HIP_MEMORY_SCOPE_AGENT);
    int g = 0;
    while (v < tgt && ++g < GUARD) {
        __builtin_amdgcn_s_sleep(SLP);
        v = __hip_atomic_load(p, __ATOMIC_RELAXED, __HIP_MEMORY_SCOPE_AGENT);
    }
}

// ---------------- prep kernel (transpose-only; wcvt moved into fused) ----------------
// 432 blocks: transpose+cvt x[B][R][8] f32 -> xth[R][B][8] f16; zero flags.
__global__ __launch_bounds__(256) void prep_kernel(
    const float* __restrict__ x, int4* __restrict__ xth4,
    int* __restrict__ flags)
{
    __shared__ __align__(16) float4 lds4[64 * 34];
    const int t = threadIdx.x;
    const int bid = blockIdx.x;

    {
        const unsigned idx = (unsigned)bid * 256u + (unsigned)t;
        if (idx < (unsigned)FLAGI) flags[idx] = 0;
    }

    const int rblk = bid >> 2;
    const int bblk = bid & 3;
    const int r0 = rblk * 64, b0 = bblk * 16;
    {
        const int rl = t & 63;
        const int bl0 = t >> 6;
#pragma unroll
        for (int kb = 0; kb < 4; ++kb) {
            const int bl = kb * 4 + bl0;
            const float4* src = (const float4*)(x + ((size_t)(b0 + bl) * RR + (r0 + rl)) * II);
            lds4[rl * 34 + bl * 2 + 0] = src[0];
            lds4[rl * 34 + bl * 2 + 1] = src[1];
        }
    }
    __syncthreads();
    {
        const int bl = t & 15;
        const int rw0 = t >> 4;
#pragma unroll
        for (int kr = 0; kr < 4; ++kr) {
            const int rw = kr * 16 + rw0;
            float4 a = lds4[rw * 34 + bl * 2 + 0];
            float4 bq = lds4[rw * 34 + bl * 2 + 1];
            HV u;
            u.h[0] = h2{(_Float16)a.x,  (_Float16)a.y};
            u.h[1] = h2{(_Float16)a.z,  (_Float16)a.w};
            u.h[2] = h2{(_Float16)bq.x, (_Float16)bq.y};
            u.h[3] = h2{(_Float16)bq.z, (_Float16)bq.w};
            xth4[(size_t)(r0 + rw) * BB + (b0 + bl)] = u.v;
        }
    }
}

// ---------------- routing iteration ----------------
// MFMA core identical to R7/R9/R10 (passed). ph = iteration index + 1.
// Entry (MODE!=0): poll rdone[c][xcd] >= ph-1 (<=9 pollers/line), then load ov.
// Exit: UNIQUE-address exchanges to pw[c][b][chunk][o] (contiguous for the
// combine reader), syncthreads (drain acks), arrival add; last arriver
// broadcasts 8 arrRep replicas.
template <int MODE>
__device__ __forceinline__ void it_phase(
    const int4* __restrict__ xth4, const int4* wlds, float* mrg,
    const float* __restrict__ ov,
    float* __restrict__ pw, float* __restrict__ pz,
    int* flags, int c, int chunk, int xcd, int t, int ph)
{
    const int wv = t >> 6;
    const int l = t & 63;
    const int b = l & 31;
    const int hi = l >> 5;
    const int aquad = (l >> 4) & 1;
    const bool aact = (aquad == hi);

    if (MODE != 0) {
        if (t == 0) pollge<8, (1 << 14)>(flags + L_RD(c, xcd), ph - 1);
        __syncthreads();   // fence: ov loads stay below the poll
    }

    float accA[8], accB[8];
#pragma unroll
    for (int j = 0; j < 8; ++j) { accA[j] = 0.f; accB[j] = 0.f; }
    float ZA = 0.f, ZB = 0.f;

    float ovA[8], ovB[8];
    if (MODE != 0) {
        const float* pa = ov + ((size_t)c * BB + b) * OO + 4 * hi;
        const float* pb = ov + ((size_t)c * BB + 32 + b) * OO + 4 * hi;
        float4 a0 = *(const float4*)(pa);
        float4 a1 = *(const float4*)(pa + 8);
        float4 b0 = *(const float4*)(pb);
        float4 b1 = *(const float4*)(pb + 8);
        ovA[0]=a0.x; ovA[1]=a0.y; ovA[2]=a0.z; ovA[3]=a0.w;
        ovA[4]=a1.x; ovA[5]=a1.y; ovA[6]=a1.z; ovA[7]=a1.w;
        ovB[0]=b0.x; ovB[1]=b0.y; ovB[2]=b0.z; ovB[3]=b0.w;
        ovB[4]=b1.x; ovB[5]=b1.y; ovB[6]=b1.z; ovB[7]=b1.w;
    }

    const int rbase = chunk * RPB2 + wv * 24;

    f32x16 cA, cB, zf;
#pragma unroll
    for (int q = 0; q < 16; ++q) { cA[q] = 0.f; cB[q] = 0.f; zf[q] = 0.f; }

    HV xc0, xc1, xn0, xn1;
    xc0.v = xth4[(size_t)(rbase + hi) * BB + b];
    xc1.v = xth4[(size_t)(rbase + hi) * BB + 32 + b];
    xn0 = xc0; xn1 = xc1;

#pragma unroll 1
    for (int g = 0; g < NG2; ++g) {
        if (g + 1 < NG2) {
            const int rn = rbase + (g + 1) * 2 + hi;
            xn0.v = xth4[(size_t)rn * BB + b];
            xn1.v = xth4[(size_t)rn * BB + 32 + b];
        }
        const int rl0 = wv * 24 + g * 2;
        HV wq;
        wq.v = wlds[(rl0 + aquad) * 16 + (l & 15)];
        if (!aact) wq.v = make_int4(0, 0, 0, 0);

        if (MODE == 0) {
            cA = __builtin_amdgcn_mfma_f32_32x32x16_f16(wq.h8, xc0.h8, cA, 0, 0, 0);
            cB = __builtin_amdgcn_mfma_f32_32x32x16_f16(wq.h8, xc1.h8, cB, 0, 0, 0);
        } else {
            f32x16 p0 = __builtin_amdgcn_mfma_f32_32x32x16_f16(wq.h8, xc0.h8, zf, 0, 0, 0);
            f32x16 p1 = __builtin_amdgcn_mfma_f32_32x32x16_f16(wq.h8, xc1.h8, zf, 0, 0, 0);
            float dA0 = 0.f, dA1 = 0.f, dB0 = 0.f, dB1 = 0.f;
#pragma unroll
            for (int j = 0; j < 8; ++j) {
                dA0 = fmaf(p0[j],     ovA[j], dA0);
                dA1 = fmaf(p0[j + 8], ovA[j], dA1);
                dB0 = fmaf(p1[j],     ovB[j], dB0);
                dB1 = fmaf(p1[j + 8], ovB[j], dB1);
            }
            dA0 += __shfl_xor(dA0, 32);
            dA1 += __shfl_xor(dA1, 32);
            dB0 += __shfl_xor(dB0, 32);
            dB1 += __shfl_xor(dB1, 32);
            const float eA0 = __expf(dA0), eA1 = __expf(dA1);
            const float eB0 = __expf(dB0), eB1 = __expf(dB1);
            ZA += eA0 + eA1; ZB += eB0 + eB1;
#pragma unroll
            for (int j = 0; j < 8; ++j) {
                accA[j] = fmaf(eA0, p0[j], fmaf(eA1, p0[j + 8], accA[j]));
                accB[j] = fmaf(eB0, p1[j], fmaf(eB1, p1[j + 8], accB[j]));
            }
        }
        xc0 = xn0; xc1 = xn1;
    }

    if (MODE == 0) {
#pragma unroll
        for (int j = 0; j < 8; ++j) {
            accA[j] = cA[j] + cA[j + 8];
            accB[j] = cB[j] + cB[j + 8];
        }
    }

    {
        float* m0 = mrg + (wv * 64 + b) * MRG_PAD + 4 * hi;
        *(float4*)(m0)     = make_float4(accA[0], accA[1], accA[2], accA[3]);
        *(float4*)(m0 + 8) = make_float4(accA[4], accA[5], accA[6], accA[7]);
        float* m1 = mrg + (wv * 64 + 32 + b) * MRG_PAD + 4 * hi;
        *(float4*)(m1)     = make_float4(accB[0], accB[1], accB[2], accB[3]);
        *(float4*)(m1 + 8) = make_float4(accB[4], accB[5], accB[6], accB[7]);
        if (MODE != 0 && hi == 0) {
            float* zr = mrg + 4 * 64 * MRG_PAD;
            zr[wv * 64 + b] = ZA;
            zr[wv * 64 + 32 + b] = ZB;
        }
    }
    __syncthreads();

    // block partial -> unique slots, TRANSPOSED layout pw[c][b][chunk][o]
    // (combine block (c,b) then reads a contiguous 72x16 f32 run)
    {
        const int b2 = t >> 2, q = t & 3;
        float4 sum = make_float4(0.f, 0.f, 0.f, 0.f);
#pragma unroll
        for (int w2 = 0; w2 < 4; ++w2) {
            const float4 v = *(const float4*)(mrg + (w2 * 64 + b2) * MRG_PAD + q * 4);
            sum.x += v.x; sum.y += v.y; sum.z += v.z; sum.w += v.w;
        }
        float* dst = pw + (((size_t)(c * BB + b2) * NCH2 + chunk) * OO) + q * 4;
        xchf2(dst + 0, sum.x, sum.y);
        xchf2(dst + 2, sum.z, sum.w);
        if (MODE != 0 && q == 0) {
            const float* zr = mrg + 4 * 64 * MRG_PAD;
            float z = 0.f;
#pragma unroll
            for (int w2 = 0; w2 < 4; ++w2) z += zr[w2 * 64 + b2];
            xchf(pz + (size_t)(c * BB + b2) * NCH2 + chunk, z);
        }
    }

    __syncthreads();   // drain exchange acks (vmcnt) before arrival
    if (t == 0) {
        const int old = addi(flags + L_ARR(c));
        if (old == NCH2 * ph - 1) {
#pragma unroll
            for (int r = 0; r < 8; ++r) xchi(flags + L_ARREP(c, r), ph);
        }
    }
}

// ---------------- combine: block (c2,b2)=bid sums 72 chunk partials + squash ----------------
template <int MODE>
__device__ __forceinline__ void combine_phase(
    const float* __restrict__ pw, const float* __restrict__ pzw,
    const float* __restrict__ addv, float* __restrict__ dst, bool coh,
    int* flags, int bid, int t, float* cl, int ph)
{
    const int c2 = bid >> 6, b2 = bid & 63;
    const int o = t & 15, g = t >> 4;

    if (t == 0) pollge<8, (1 << 14)>(flags + L_ARREP(c2, bid & 7), ph);
    __syncthreads();   // fence: partial loads stay below the poll

    // contiguous 72x16 run for this (c2,b2)
    const float* base = pw + (size_t)(c2 * BB + b2) * NCH2 * OO;
    const float* zb   = pzw + (size_t)(c2 * BB + b2) * NCH2;
    float s = 0.f, zl = 0.f;
#pragma unroll
    for (int k = 0; k < 5; ++k) {
        const int rid = g + k * 16;
        if (rid < NCH2) {
            s += base[rid * OO + o];
            if (MODE != 0 && o == 0) zl += zb[rid];
        }
    }
    cl[t] = s;
    if (MODE != 0 && o == 0) cl[256 + g] = zl;
    __syncthreads();

    if (g == 0) {
#pragma unroll
        for (int k = 1; k < 16; ++k) s += cl[k * 16 + o];
        if (MODE != 0) {
            float Zt = 0.f;
#pragma unroll
            for (int k = 0; k < 16; ++k) Zt += cl[256 + k];
            s /= Zt;
        } else {
            s *= (1.0f / RR);
        }
        float sq = s * s;
#pragma unroll
        for (int w = 1; w < 16; w <<= 1) sq += __shfl_xor(sq, w);
        float val = s * sqrtf(sq) / (1.f + sq);
        if (MODE == 1) val += addv[(size_t)bid * OO + o];
        if (coh) xchf(dst + (size_t)bid * OO + o, val);
        else     dst[(size_t)bid * OO + o] = val;   // final out: dispatch-end flush
    }
    __syncthreads();   // drain v-write acks before completion count

    if (MODE != 2 && t == 0) {
        const int old = addi(flags + L_CD(c2));
        if (old == 64 * ph - 1) {                // 64 combine blocks per class
#pragma unroll
            for (int r = 0; r < 8; ++r) xchi(flags + L_RD(c2, r), ph);
        }
    }
}

// ---------------- fused routing kernel ----------------
// 720 blocks co-resident (LDS 47.2KB -> 3/CU, capacity 768). W staged once,
// DIRECTLY from f32 input (wcvt pass eliminated: the wh f16 intermediate was
// a pure 53MB roundtrip since each block only consumes its own tile).
// XCD-bijective swizzle (R9-proven). Producer-consumer flags (R10-proven).
__global__ __launch_bounds__(256, 3) void fused_kernel(
    const int4* __restrict__ xth4, const float* __restrict__ w,
    float* pw0, float* pw1, float* pw2, float* pz1, float* pz2,
    float* v0, float* outsum, float* out, int* flags)
{
    __shared__ __align__(16) int4 wlds[WTILE_I4];   // 24576 B
    __shared__ __align__(16) float mrg[MRGF];       // 21504 B
    __shared__ float cl[272];                       //  1088 B

    const int bid = blockIdx.x;
    const int t = threadIdx.x;
    const int xcd = bid & 7;
    const int u = xcd * 90 + (bid >> 3);
    const int chunk = u / 10;
    const int c = u - chunk * 10;

    // stage the 96-route W tile f32 -> f16 [r][o][i] in LDS:
    // 12 passes x 256 coalesced float4 (W[c][r][i][o], float4 j in route:
    // i = (t>>2)&7, o0 = (t&3)*4 since 256 % 32 == 0)
    {
        const float4* wsrc = (const float4*)(w + ((size_t)c * RR + (size_t)chunk * RPB2) * 128);
        _Float16* wl = (_Float16*)wlds;
        const int i  = (t >> 2) & 7;
        const int o0 = (t & 3) * 4;
#pragma unroll 6
        for (int p = 0; p < 12; ++p) {
            const float4 v = wsrc[p * 256 + t];
            const int rp = (p * 256 + t) >> 5;
            wl[(rp * 16 + o0 + 0) * 8 + i] = (_Float16)v.x;
            wl[(rp * 16 + o0 + 1) * 8 + i] = (_Float16)v.y;
            wl[(rp * 16 + o0 + 2) * 8 + i] = (_Float16)v.z;
            wl[(rp * 16 + o0 + 3) * 8 + i] = (_Float16)v.w;
        }
    }
    __syncthreads();

    it_phase<0>(xth4, wlds, mrg, nullptr, pw0, nullptr, flags, c, chunk, xcd, t, 1);
    if (bid < CC * BB) combine_phase<0>(pw0, nullptr, nullptr, v0, true, flags, bid, t, cl, 1);
    it_phase<1>(xth4, wlds, mrg, v0, pw1, pz1, flags, c, chunk, xcd, t, 2);
    if (bid < CC * BB) combine_phase<1>(pw1, pz1, v0, outsum, true, flags, bid, t, cl, 2);
    it_phase<2>(xth4, wlds, mrg, outsum, pw2, pz2, flags, c, chunk, xcd, t, 3);
    if (bid < CC * BB) combine_phase<2>(pw2, pz2, nullptr, out, false, flags, bid, t, cl, 3);
}

extern "C" void kernel_launch(void* const* d_in, const int* in_sizes, int n_in,
                              void* d_out, int out_size, void* d_ws, size_t ws_size,
                              hipStream_t stream)
{
    const float* x = (const float*)d_in[0];
    const float* w = (const float*)d_in[1];
    float* out = (float*)d_out;

    float* ws = (float*)d_ws;
    float* xth    = ws;                                   // RR*BB*4 f32 slots (f16 x2)
    float* pw0    = xth + (size_t)RR * BB * 4;            // PWW
    float* pw1    = pw0 + PWW;                            // PWW
    float* pw2    = pw1 + PWW;                            // PWW
    float* pz1    = pw2 + PWW;                            // PZW
    float* pz2    = pz1 + PZW;                            // PZW
    float* v0     = pz2 + PZW;                            // CC*BB*OO
    float* outsum = v0 + CC * BB * OO;                    // CC*BB*OO
    int*   flags  = (int*)(outsum + CC * BB * OO);        // FLAGI ints

    int4* xth4 = (int4*)xth;

    prep_kernel<<<dim3(432), dim3(256), 0, stream>>>(x, xth4, flags);
    fused_kernel<<<dim3(NBLK), dim3(256), 0, stream>>>(
        xth4, w, pw0, pw1, pw2, pz1, pz2, v0, outsum, out, flags);
}